// Round 1
// baseline (1003.416 us; speedup 1.0000x reference)
//
#include <hip/hip_runtime.h>
#include <math.h>

#define BATCH 8192
#define D_G   4611
#define KN    25
#define KE    28   // padded row: 25 weights, [25]=bias/alpha slot, [26..27]=0

// workspace offsets (floats), all 32-float aligned
#define WS_WCAT   0        // [25][4611]
#define WS_BCAT   115296   // [4611]
#define WS_WCATT  119936   // [4611][28]
#define WS_M      249056   // [25][25]
#define WS_C      249696   // [25]
#define WS_BB     249728   // [1]
#define WS_P      249760   // [8192][25]  P = n @ M
#define WS_Q      454560   // [8192]      q_i = n_i M n_i^T
#define WS_G2     462752   // [8192]      |G_j|^2
#define WS_R      470944   // [8192][25]  r = prior @ Wcat^T
#define WS_T      675744   // [8192]      |p_i|^2 - 2 p_i.bcat
#define WS_WP2    683936   // [8192]      min sq (bits) prior->G
#define WS_WW2    692128   // [8192]      min sq (bits) G->G (i!=j)
#define WS_ACC    700320   // recon accumulator

__device__ inline float eluf(float x) { return x > 0.f ? x : expm1f(x); }

__device__ inline float vdot28(const float4* __restrict__ w, const float* nx) {
  float acc = 0.f;
#pragma unroll
  for (int q = 0; q < 7; q++) {
    float4 a = w[q];
    acc += a.x * nx[4*q] + a.y * nx[4*q+1] + a.z * nx[4*q+2] + a.w * nx[4*q+3];
  }
  return acc;
}

__global__ void k_init(float* ws) {
  int idx = blockIdx.x * 256 + threadIdx.x;
  unsigned int* u = (unsigned int*)ws;
  if (idx < BATCH)            u[WS_WP2 + idx] = 0x7F7FFFFFu;          // FLT_MAX bits
  else if (idx < 2 * BATCH)   u[WS_WW2 + (idx - BATCH)] = 0x7F7FFFFFu;
  else if (idx == 2 * BATCH)  ws[WS_ACC] = 0.f;
}

__global__ void k_build(const float* __restrict__ w1W, const float* __restrict__ w1b,
                        const float* __restrict__ b1W, const float* __restrict__ b1b,
                        const float* __restrict__ w2W, const float* __restrict__ w2b,
                        const float* __restrict__ b2W, const float* __restrict__ b2b,
                        const float* __restrict__ w3W, const float* __restrict__ w3b,
                        const float* __restrict__ b3W, const float* __restrict__ b3b,
                        float* ws) {
  int idx = blockIdx.x * 256 + threadIdx.x;
  if (idx >= KN * D_G) return;
  int k = idx / D_G;
  int d = idx - k * D_G;
  float wv, bv;
  if (d < 192)       { int c = d;        wv = w1W[k*192  + c]; bv = w1b[c]; }
  else if (d < 256)  { int c = d - 192;  wv = b1W[k*64   + c]; bv = b1b[c]; }
  else if (d < 4352) { int c = d - 256;  wv = w2W[k*4096 + c]; bv = w2b[c]; }
  else if (d < 4416) { int c = d - 4352; wv = b2W[k*64   + c]; bv = b2b[c]; }
  else if (d < 4608) { int c = d - 4416; wv = w3W[k*192  + c]; bv = w3b[c]; }
  else               { int c = d - 4608; wv = b3W[k*3    + c]; bv = b3b[c]; }
  ws[WS_WCAT  + k * D_G + d] = wv;
  ws[WS_WCATT + d * KE  + k] = wv;
  if (k == 0) {
    ws[WS_BCAT + d] = bv;
    ws[WS_WCATT + d * KE + 25] = bv;
    ws[WS_WCATT + d * KE + 26] = 0.f;
    ws[WS_WCATT + d * KE + 27] = 0.f;
  }
}

// M = Wcat Wcat^T (25x25), c = Wcat bcat, bb = |bcat|^2
__global__ void k_M(float* ws) {
  const float* Wc = ws + WS_WCAT;
  const float* bc = ws + WS_BCAT;
  __shared__ float sred[256];
  int a = blockIdx.x, t = threadIdx.x;
  if (a < 25) {
    float acc[26];
#pragma unroll
    for (int v = 0; v < 26; v++) acc[v] = 0.f;
    for (int d = t; d < D_G; d += 256) {
      float va = Wc[a * D_G + d];
#pragma unroll
      for (int b = 0; b < 25; b++) acc[b] += va * Wc[b * D_G + d];
      acc[25] += va * bc[d];
    }
    for (int v = 0; v < 26; v++) {
      sred[t] = acc[v]; __syncthreads();
      for (int off = 128; off > 0; off >>= 1) { if (t < off) sred[t] += sred[t + off]; __syncthreads(); }
      if (t == 0) { if (v < 25) ws[WS_M + a * 25 + v] = sred[0]; else ws[WS_C + a] = sred[0]; }
      __syncthreads();
    }
  } else {
    float acc = 0.f;
    for (int d = t; d < D_G; d += 256) { float b = bc[d]; acc += b * b; }
    sred[t] = acc; __syncthreads();
    for (int off = 128; off > 0; off >>= 1) { if (t < off) sred[t] += sred[t + off]; __syncthreads(); }
    if (t == 0) ws[WS_BB] = sred[0];
  }
}

// P = n @ M, q = nMn^T, g2 = |G|^2
__global__ void k_persample(const float* __restrict__ n, float* ws) {
  int j = blockIdx.x * 256 + threadIdx.x;
  if (j >= BATCH) return;
  const float* M  = ws + WS_M;
  const float* cv = ws + WS_C;
  float nr[25];
#pragma unroll
  for (int k = 0; k < 25; k++) nr[k] = n[j * 25 + k];
  float q = 0.f;
  for (int k2 = 0; k2 < 25; k2++) {
    float p = 0.f;
#pragma unroll
    for (int k1 = 0; k1 < 25; k1++) p += nr[k1] * M[k1 * 25 + k2];
    ws[WS_P + j * 25 + k2] = p;
    q += p * nr[k2];
  }
  float nc = 0.f;
#pragma unroll
  for (int k = 0; k < 25; k++) nc += nr[k] * cv[k];
  ws[WS_Q  + j] = q;
  ws[WS_G2 + j] = q + 2.f * nc + ws[WS_BB];
}

// r_i = prior_i @ Wcat^T, T_i = |p_i|^2 - 2 p_i.bcat   (8 rows/block, 32 lanes/row)
__global__ __launch_bounds__(256) void k_prior(const float* __restrict__ prior, float* ws) {
  const float* Wc = ws + WS_WCAT;
  const float* bc = ws + WS_BCAT;
  int g = threadIdx.x >> 5, l = threadIdx.x & 31;
  int i = blockIdx.x * 8 + g;
  float r[25];
#pragma unroll
  for (int k = 0; k < 25; k++) r[k] = 0.f;
  float s = 0.f, p2 = 0.f;
  const float* prow = prior + (size_t)i * D_G;
  for (int d = l; d < D_G; d += 32) {
    float pv = prow[d];
    p2 += pv * pv;
    s  += pv * bc[d];
#pragma unroll
    for (int k = 0; k < 25; k++) r[k] += pv * Wc[k * D_G + d];
  }
#pragma unroll
  for (int k = 0; k < 25; k++)
    for (int off = 16; off > 0; off >>= 1) r[k] += __shfl_down(r[k], off, 32);
  for (int off = 16; off > 0; off >>= 1) { s += __shfl_down(s, off, 32); p2 += __shfl_down(p2, off, 32); }
  if (l == 0) {
#pragma unroll
    for (int k = 0; k < 25; k++) ws[WS_R + i * 25 + k] = r[k];
    ws[WS_T + i] = p2 - 2.f * s;
  }
}

// column-min over i of (alpha_i + beta_j - 2 A_i.n_j), clamped >= 0.
// LDS row: [A_i(25), -alpha_i/2, 0, 0]; n_ext[25]=1 folds alpha into the dot.
template <int SKIP>
__global__ __launch_bounds__(256) void k_pair(const float* __restrict__ A, const float* alpha,
                                              const float* __restrict__ Bn, const float* beta,
                                              unsigned int* __restrict__ outm) {
  __shared__ float lA[512 * KE];
  int t = threadIdx.x;
  int i0 = blockIdx.y * 512;
  for (int idx = t; idx < 512 * KE; idx += 256) {
    int row = idx / KE, kk = idx - row * KE;
    float v = 0.f;
    if (kk < 25) v = A[(i0 + row) * 25 + kk];
    else if (kk == 25) v = -0.5f * alpha[i0 + row];
    lA[idx] = v;
  }
  int j  = blockIdx.x * 128 + (t & 127);
  int ig = t >> 7;
  float nx[KE];
#pragma unroll
  for (int k = 0; k < 25; k++) nx[k] = Bn[j * 25 + k];
  nx[25] = 1.f; nx[26] = 0.f; nx[27] = 0.f;
  float bj = beta[j];
  __syncthreads();
  float mn = 3.402823466e38f;
  for (int it = 0; it < 256; ++it) {
    int ir = ig + 2 * it;                       // wave-uniform
    const float4* ar = (const float4*)(lA + ir * KE);
    float dot = vdot28(ar, nx);                 // = A_i.n_j - alpha_i/2
    float sq = bj - 2.f * dot;                  // = alpha_i + beta_j - 2 A_i.n_j
    sq = fmaxf(sq, 0.f);
    if (!SKIP || (i0 + ir != j)) mn = fminf(mn, sq);
  }
  atomicMin(&outm[j], __float_as_uint(mn));     // non-negative floats: uint order == float order
}

// hyper-decoder: 32 samples/block; every generated weight = one 28-dot against WcatT
__global__ __launch_bounds__(256) void k_decode(const float* __restrict__ n, const float* __restrict__ z,
                                                const float* __restrict__ znext,
                                                float* __restrict__ out, float* ws) {
  __shared__ float h1[32][65];
  __shared__ float h2[32][65];
  __shared__ float zsq[32][3];
  __shared__ float red[32];
  int t = threadIdx.x;
  int sl = t & 31, rg = t >> 5;
  int s = blockIdx.x * 32 + sl;
  const float4* WT = (const float4*)(ws + WS_WCATT);
  float nx[KE];
#pragma unroll
  for (int k = 0; k < 25; k++) nx[k] = n[s * 25 + k];
  nx[25] = 1.f; nx[26] = 0.f; nx[27] = 0.f;
  float zr[3];
#pragma unroll
  for (int d = 0; d < 3; d++) zr[d] = z[s * 3 + d];
  // phase 1: h1 = elu(W1 z + B1)
  for (int rr = 0; rr < 8; rr++) {
    int r = rg * 8 + rr;
    float acc = vdot28(WT + (size_t)(192 + r) * 7, nx);           // B1
#pragma unroll
    for (int d = 0; d < 3; d++)
      acc += vdot28(WT + (size_t)(r * 3 + d) * 7, nx) * zr[d];    // W1
    h1[sl][r] = eluf(acc);
  }
  __syncthreads();
  // phase 2: h2 = elu(W2 h1 + B2)
  for (int rr = 0; rr < 8; rr++) {
    int r = rg * 8 + rr;
    float acc = vdot28(WT + (size_t)(4352 + r) * 7, nx);          // B2
    for (int c = 0; c < 64; c++)
      acc += vdot28(WT + (size_t)(256 + r * 64 + c) * 7, nx) * h1[sl][c];  // W2
    h2[sl][r] = eluf(acc);
  }
  __syncthreads();
  // phase 3: z_hat = W3 h2 + B3
  if (rg < 3) {
    float acc = vdot28(WT + (size_t)(4608 + rg) * 7, nx);         // B3
    for (int c = 0; c < 64; c++)
      acc += vdot28(WT + (size_t)(4416 + rg * 64 + c) * 7, nx) * h2[sl][c]; // W3
    out[2 + s * 3 + rg] = acc;
    float dz = acc - znext[s * 3 + rg];
    zsq[sl][rg] = dz * dz;
  }
  __syncthreads();
  if (t < 32) red[t] = zsq[t][0] + zsq[t][1] + zsq[t][2];
  __syncthreads();
  if (t == 0) {
    float sum = 0.f;
    for (int u2 = 0; u2 < 32; u2++) sum += red[u2];
    atomicAdd(ws + WS_ACC, sum);
  }
}

__global__ void k_finish(float* ws, float* __restrict__ out) {
  __shared__ float sred[256];
  int t = threadIdx.x;
  float part = 0.f;
  for (int j = t; j < BATCH; j += 256) {
    float wp2 = ws[WS_WP2 + j];               // clamped >= 0 already
    float ww2 = ws[WS_WW2 + j];
    float wp = sqrtf(wp2 + 1e-8f);
    float ww = sqrtf(ww2 + 1e-8f);
    part += logf(wp / (ww + 1e-8f) + 1e-8f);
  }
  sred[t] = part; __syncthreads();
  for (int off = 128; off > 0; off >>= 1) { if (t < off) sred[t] += sred[t + off]; __syncthreads(); }
  if (t == 0) {
    float kl = sred[0] / (float)BATCH * (float)D_G + logf((float)BATCH / (float)(BATCH - 1));
    out[0] = ws[WS_ACC] / (float)BATCH;       // recon
    out[1] = kl;
  }
}

extern "C" void kernel_launch(void* const* d_in, const int* in_sizes, int n_in,
                              void* d_out, int out_size, void* d_ws, size_t ws_size,
                              hipStream_t stream) {
  (void)in_sizes; (void)n_in; (void)out_size; (void)ws_size;
  const float* z     = (const float*)d_in[0];
  const float* znext = (const float*)d_in[1];
  const float* n     = (const float*)d_in[2];
  const float* prior = (const float*)d_in[3];
  const float* w1W = (const float*)d_in[4];  const float* w1b = (const float*)d_in[5];
  const float* b1W = (const float*)d_in[6];  const float* b1b = (const float*)d_in[7];
  const float* w2W = (const float*)d_in[8];  const float* w2b = (const float*)d_in[9];
  const float* b2W = (const float*)d_in[10]; const float* b2b = (const float*)d_in[11];
  const float* w3W = (const float*)d_in[12]; const float* w3b = (const float*)d_in[13];
  const float* b3W = (const float*)d_in[14]; const float* b3b = (const float*)d_in[15];
  float* out = (float*)d_out;
  float* ws  = (float*)d_ws;

  k_init<<<dim3(65), dim3(256), 0, stream>>>(ws);
  k_build<<<dim3((KN * D_G + 255) / 256), dim3(256), 0, stream>>>(
      w1W, w1b, b1W, b1b, w2W, w2b, b2W, b2b, w3W, w3b, b3W, b3b, ws);
  k_M<<<dim3(26), dim3(256), 0, stream>>>(ws);
  k_persample<<<dim3(32), dim3(256), 0, stream>>>(n, ws);
  k_prior<<<dim3(1024), dim3(256), 0, stream>>>(prior, ws);
  k_pair<1><<<dim3(64, 16), dim3(256), 0, stream>>>(ws + WS_P, ws + WS_Q, n, ws + WS_Q,
                                                    (unsigned int*)(ws + WS_WW2));
  k_pair<0><<<dim3(64, 16), dim3(256), 0, stream>>>(ws + WS_R, ws + WS_T, n, ws + WS_G2,
                                                    (unsigned int*)(ws + WS_WP2));
  k_decode<<<dim3(256), dim3(256), 0, stream>>>(n, z, znext, out, ws);
  k_finish<<<dim3(1), dim3(256), 0, stream>>>(ws, out);
}

// Round 2
// 810.098 us; speedup vs baseline: 1.2386x; 1.2386x over previous
//
#include <hip/hip_runtime.h>
#include <math.h>

#define BATCH 8192
#define D_G   4611
#define KN    25
#define KE    28   // padded row: 25 weights, [25]=bias/alpha slot, [26..27]=0

// workspace offsets (floats)
#define WS_WCAT   0        // [25][4611]
#define WS_BCAT   115296   // [4611]
#define WS_WCATT  119936   // [4611][28]   row d = [w[0..24], bias, 0, 0]
#define WS_M      249056   // [25][25]
#define WS_C      249696   // [25]
#define WS_BB     249728   // [1]
#define WS_PPAD   249760   // [8192][28]   [25] = -q/2
#define WS_Q      479136   // [8192]
#define WS_G2     487328   // [8192]
#define WS_RPAD   495520   // [8192][28]   [25] = -T/2
#define WS_WP2    724896   // [8192] min sq bits (prior->G)
#define WS_WW2    733088   // [8192] min sq bits (G->G, i!=j)
#define WS_ACC    741280   // recon accumulator
#define WS_H1T    741312   // [64][8192]
#define WS_H2T    1265600  // [64][8192]

__device__ inline float eluf(float x) { return x > 0.f ? x : expm1f(x); }

// dot of a wave-uniform 28-float row (25 weights + bias at [25]) with per-lane nx[25].
// Row address is forced scalar -> s_load stream, FMAs use SGPR operand.
__device__ inline float sdot26(const float* __restrict__ WT, int rowidx, const float* nx) {
  const float* row = WT + (size_t)__builtin_amdgcn_readfirstlane(rowidx) * KE;
  float acc = row[25];
#pragma unroll
  for (int k = 0; k < 25; k++) acc = fmaf(row[k], nx[k], acc);
  return acc;
}

__global__ void k_init(float* ws) {
  int idx = blockIdx.x * 256 + threadIdx.x;
  unsigned int* u = (unsigned int*)ws;
  if (idx < BATCH)            u[WS_WP2 + idx] = 0x7F7FFFFFu;
  else if (idx < 2 * BATCH)   u[WS_WW2 + (idx - BATCH)] = 0x7F7FFFFFu;
  else if (idx == 2 * BATCH)  ws[WS_ACC] = 0.f;
}

__global__ void k_build(const float* __restrict__ w1W, const float* __restrict__ w1b,
                        const float* __restrict__ b1W, const float* __restrict__ b1b,
                        const float* __restrict__ w2W, const float* __restrict__ w2b,
                        const float* __restrict__ b2W, const float* __restrict__ b2b,
                        const float* __restrict__ w3W, const float* __restrict__ w3b,
                        const float* __restrict__ b3W, const float* __restrict__ b3b,
                        float* ws) {
  int idx = blockIdx.x * 256 + threadIdx.x;
  if (idx >= KN * D_G) return;
  int k = idx / D_G;
  int d = idx - k * D_G;
  float wv, bv;
  if (d < 192)       { int c = d;        wv = w1W[k*192  + c]; bv = w1b[c]; }
  else if (d < 256)  { int c = d - 192;  wv = b1W[k*64   + c]; bv = b1b[c]; }
  else if (d < 4352) { int c = d - 256;  wv = w2W[k*4096 + c]; bv = w2b[c]; }
  else if (d < 4416) { int c = d - 4352; wv = b2W[k*64   + c]; bv = b2b[c]; }
  else if (d < 4608) { int c = d - 4416; wv = w3W[k*192  + c]; bv = w3b[c]; }
  else               { int c = d - 4608; wv = b3W[k*3    + c]; bv = b3b[c]; }
  ws[WS_WCAT  + k * D_G + d] = wv;
  ws[WS_WCATT + d * KE  + k] = wv;
  if (k == 0) {
    ws[WS_BCAT + d] = bv;
    ws[WS_WCATT + d * KE + 25] = bv;
    ws[WS_WCATT + d * KE + 26] = 0.f;
    ws[WS_WCATT + d * KE + 27] = 0.f;
  }
}

// M = Wcat Wcat^T (25x25), c = Wcat bcat, bb = |bcat|^2
__global__ void k_M(float* ws) {
  const float* Wc = ws + WS_WCAT;
  const float* bc = ws + WS_BCAT;
  __shared__ float sred[256];
  int a = blockIdx.x, t = threadIdx.x;
  if (a < 25) {
    float acc[26];
#pragma unroll
    for (int v = 0; v < 26; v++) acc[v] = 0.f;
    for (int d = t; d < D_G; d += 256) {
      float va = Wc[a * D_G + d];
#pragma unroll
      for (int b = 0; b < 25; b++) acc[b] += va * Wc[b * D_G + d];
      acc[25] += va * bc[d];
    }
    for (int v = 0; v < 26; v++) {
      sred[t] = acc[v]; __syncthreads();
      for (int off = 128; off > 0; off >>= 1) { if (t < off) sred[t] += sred[t + off]; __syncthreads(); }
      if (t == 0) { if (v < 25) ws[WS_M + a * 25 + v] = sred[0]; else ws[WS_C + a] = sred[0]; }
      __syncthreads();
    }
  } else {
    float acc = 0.f;
    for (int d = t; d < D_G; d += 256) { float b = bc[d]; acc += b * b; }
    sred[t] = acc; __syncthreads();
    for (int off = 128; off > 0; off >>= 1) { if (t < off) sred[t] += sred[t + off]; __syncthreads(); }
    if (t == 0) ws[WS_BB] = sred[0];
  }
}

// PPAD rows, q, g2
__global__ void k_persample(const float* __restrict__ n, float* ws) {
  int j = blockIdx.x * 256 + threadIdx.x;
  if (j >= BATCH) return;
  const float* M  = ws + WS_M;
  const float* cv = ws + WS_C;
  float nr[25];
#pragma unroll
  for (int k = 0; k < 25; k++) nr[k] = n[j * 25 + k];
  float q = 0.f;
  for (int k2 = 0; k2 < 25; k2++) {
    float p = 0.f;
#pragma unroll
    for (int k1 = 0; k1 < 25; k1++) p += nr[k1] * M[k1 * 25 + k2];
    ws[WS_PPAD + j * KE + k2] = p;
    q += p * nr[k2];
  }
  float nc = 0.f;
#pragma unroll
  for (int k = 0; k < 25; k++) nc += nr[k] * cv[k];
  ws[WS_PPAD + j * KE + 25] = -0.5f * q;
  ws[WS_PPAD + j * KE + 26] = 0.f;
  ws[WS_PPAD + j * KE + 27] = 0.f;
  ws[WS_Q  + j] = q;
  ws[WS_G2 + j] = q + 2.f * nc + ws[WS_BB];
}

// RPAD rows: r_i = prior_i @ Wcat^T, [25] = -0.5*(|p_i|^2 - 2 p_i.bcat)
__global__ __launch_bounds__(256) void k_prior(const float* __restrict__ prior, float* ws) {
  const float* Wc = ws + WS_WCAT;
  const float* bc = ws + WS_BCAT;
  int g = threadIdx.x >> 5, l = threadIdx.x & 31;
  int i = blockIdx.x * 8 + g;
  float r[25];
#pragma unroll
  for (int k = 0; k < 25; k++) r[k] = 0.f;
  float s = 0.f, p2 = 0.f;
  const float* prow = prior + (size_t)i * D_G;
  for (int d = l; d < D_G; d += 32) {
    float pv = prow[d];
    p2 += pv * pv;
    s  += pv * bc[d];
#pragma unroll
    for (int k = 0; k < 25; k++) r[k] += pv * Wc[k * D_G + d];
  }
#pragma unroll
  for (int k = 0; k < 25; k++)
    for (int off = 16; off > 0; off >>= 1) r[k] += __shfl_down(r[k], off, 32);
  for (int off = 16; off > 0; off >>= 1) { s += __shfl_down(s, off, 32); p2 += __shfl_down(p2, off, 32); }
  if (l == 0) {
#pragma unroll
    for (int k = 0; k < 25; k++) ws[WS_RPAD + i * KE + k] = r[k];
    ws[WS_RPAD + i * KE + 25] = -0.5f * (p2 - 2.f * s);
    ws[WS_RPAD + i * KE + 26] = 0.f;
    ws[WS_RPAD + i * KE + 27] = 0.f;
  }
}

// min over i of (alpha_i + beta_j - 2 A_i.n_j), clamped >= 0. A rows streamed via SGPRs.
template <int SKIP>
__global__ __launch_bounds__(256) void k_pair(const float* __restrict__ APAD,
                                              const float* __restrict__ Bn,
                                              const float* __restrict__ beta,
                                              unsigned int* __restrict__ outm) {
  int t = threadIdx.x;
  int j = blockIdx.x * 256 + t;
  float nx[25];
#pragma unroll
  for (int k = 0; k < 25; k++) nx[k] = Bn[j * 25 + k];
  float bj = beta[j];
  float mn = 3.402823466e38f;
  int i0 = blockIdx.y * 512;
#pragma unroll 2
  for (int it = 0; it < 512; ++it) {
    int i = i0 + it;                               // wave-uniform
    const float* row = APAD + (size_t)__builtin_amdgcn_readfirstlane(i) * KE;
    float acc = row[25];
#pragma unroll
    for (int k = 0; k < 25; k++) acc = fmaf(row[k], nx[k], acc);
    float sq = fmaf(-2.f, acc, bj);
    sq = fmaxf(sq, 0.f);
    bool skip = SKIP && (i == j);
    mn = skip ? mn : fminf(mn, sq);
  }
  atomicMin(&outm[j], __float_as_uint(mn));
}

// decode phase 1: h1 = elu(W1 z + B1); 1 wave/block, 64 samples, 16 rows
__global__ __launch_bounds__(64) void kd1(const float* __restrict__ n, const float* __restrict__ z,
                                          const float* __restrict__ ws_wt, float* __restrict__ h1t) {
  int s = blockIdx.x * 64 + threadIdx.x;
  int rb = blockIdx.y * 16;
  float nx[25];
#pragma unroll
  for (int k = 0; k < 25; k++) nx[k] = n[s * 25 + k];
  float zr[3];
#pragma unroll
  for (int d = 0; d < 3; d++) zr[d] = z[s * 3 + d];
  for (int r = 0; r < 16; r++) {
    int rr = rb + r;
    float acc = sdot26(ws_wt, 192 + rr, nx);                      // B1
#pragma unroll
    for (int d = 0; d < 3; d++)
      acc = fmaf(sdot26(ws_wt, rr * 3 + d, nx), zr[d], acc);      // W1
    h1t[rr * BATCH + s] = eluf(acc);
  }
}

// decode phase 2: h2 = elu(W2 h1 + B2); 1 wave/block, 64 samples, 4 rows
__global__ __launch_bounds__(64) void kd2(const float* __restrict__ n,
                                          const float* __restrict__ ws_wt,
                                          const float* __restrict__ h1t, float* __restrict__ h2t) {
  int s = blockIdx.x * 64 + threadIdx.x;
  int rb = blockIdx.y * 4;
  float nx[25];
#pragma unroll
  for (int k = 0; k < 25; k++) nx[k] = n[s * 25 + k];
  float acc[4];
#pragma unroll
  for (int r = 0; r < 4; r++) acc[r] = sdot26(ws_wt, 4352 + rb + r, nx);   // B2
  for (int c = 0; c < 64; c++) {
    float h1c = h1t[c * BATCH + s];
#pragma unroll
    for (int r = 0; r < 4; r++) {
      float w = sdot26(ws_wt, 256 + (rb + r) * 64 + c, nx);                // W2
      acc[r] = fmaf(w, h1c, acc[r]);
    }
  }
#pragma unroll
  for (int r = 0; r < 4; r++) h2t[(rb + r) * BATCH + s] = eluf(acc[r]);
}

// decode phase 3: z_hat = W3 h2 + B3, recon partial; 1 wave/block, 64 samples, 1 row
__global__ __launch_bounds__(64) void kd3(const float* __restrict__ n,
                                          const float* __restrict__ znext,
                                          const float* __restrict__ ws_wt,
                                          const float* __restrict__ h2t,
                                          float* __restrict__ out, float* __restrict__ accum) {
  int s = blockIdx.x * 64 + threadIdx.x;
  int r = blockIdx.y;
  float nx[25];
#pragma unroll
  for (int k = 0; k < 25; k++) nx[k] = n[s * 25 + k];
  float acc = sdot26(ws_wt, 4608 + r, nx);                                 // B3
  for (int c = 0; c < 64; c++)
    acc = fmaf(sdot26(ws_wt, 4416 + r * 64 + c, nx), h2t[c * BATCH + s], acc); // W3
  out[2 + s * 3 + r] = acc;
  float dz = acc - znext[s * 3 + r];
  float v = dz * dz;
#pragma unroll
  for (int off = 32; off > 0; off >>= 1) v += __shfl_down(v, off, 64);
  if (threadIdx.x == 0) atomicAdd(accum, v);
}

__global__ void k_finish(float* ws, float* __restrict__ out) {
  __shared__ float sred[256];
  int t = threadIdx.x;
  float part = 0.f;
  for (int j = t; j < BATCH; j += 256) {
    float wp2 = ws[WS_WP2 + j];
    float ww2 = ws[WS_WW2 + j];
    float wp = sqrtf(wp2 + 1e-8f);
    float ww = sqrtf(ww2 + 1e-8f);
    part += logf(wp / (ww + 1e-8f) + 1e-8f);
  }
  sred[t] = part; __syncthreads();
  for (int off = 128; off > 0; off >>= 1) { if (t < off) sred[t] += sred[t + off]; __syncthreads(); }
  if (t == 0) {
    float kl = sred[0] / (float)BATCH * (float)D_G + logf((float)BATCH / (float)(BATCH - 1));
    out[0] = ws[WS_ACC] / (float)BATCH;
    out[1] = kl;
  }
}

extern "C" void kernel_launch(void* const* d_in, const int* in_sizes, int n_in,
                              void* d_out, int out_size, void* d_ws, size_t ws_size,
                              hipStream_t stream) {
  (void)in_sizes; (void)n_in; (void)out_size; (void)ws_size;
  const float* z     = (const float*)d_in[0];
  const float* znext = (const float*)d_in[1];
  const float* n     = (const float*)d_in[2];
  const float* prior = (const float*)d_in[3];
  const float* w1W = (const float*)d_in[4];  const float* w1b = (const float*)d_in[5];
  const float* b1W = (const float*)d_in[6];  const float* b1b = (const float*)d_in[7];
  const float* w2W = (const float*)d_in[8];  const float* w2b = (const float*)d_in[9];
  const float* b2W = (const float*)d_in[10]; const float* b2b = (const float*)d_in[11];
  const float* w3W = (const float*)d_in[12]; const float* w3b = (const float*)d_in[13];
  const float* b3W = (const float*)d_in[14]; const float* b3b = (const float*)d_in[15];
  float* out = (float*)d_out;
  float* ws  = (float*)d_ws;

  k_init<<<dim3(65), dim3(256), 0, stream>>>(ws);
  k_build<<<dim3((KN * D_G + 255) / 256), dim3(256), 0, stream>>>(
      w1W, w1b, b1W, b1b, w2W, w2b, b2W, b2b, w3W, w3b, b3W, b3b, ws);
  k_M<<<dim3(26), dim3(256), 0, stream>>>(ws);
  k_persample<<<dim3(32), dim3(256), 0, stream>>>(n, ws);
  k_prior<<<dim3(1024), dim3(256), 0, stream>>>(prior, ws);
  k_pair<1><<<dim3(32, 16), dim3(256), 0, stream>>>(ws + WS_PPAD, n, ws + WS_Q,
                                                    (unsigned int*)(ws + WS_WW2));
  k_pair<0><<<dim3(32, 16), dim3(256), 0, stream>>>(ws + WS_RPAD, n, ws + WS_G2,
                                                    (unsigned int*)(ws + WS_WP2));
  kd1<<<dim3(128, 4), dim3(64), 0, stream>>>(n, z, ws + WS_WCATT, ws + WS_H1T);
  kd2<<<dim3(128, 16), dim3(64), 0, stream>>>(n, ws + WS_WCATT, ws + WS_H1T, ws + WS_H2T);
  kd3<<<dim3(128, 3), dim3(64), 0, stream>>>(n, znext, ws + WS_WCATT, ws + WS_H2T, out, ws + WS_ACC);
  k_finish<<<dim3(1), dim3(256), 0, stream>>>(ws, out);
}

// Round 3
// 711.466 us; speedup vs baseline: 1.4103x; 1.1386x over previous
//
#include <hip/hip_runtime.h>
#include <math.h>

#define BATCH 8192
#define D_G   4611
#define DGP   4624   // padded Wcat row stride (multiple of 16 floats for aligned float4)
#define KN    25
#define KE    28     // padded row: 25 weights, [25]=bias/alpha slot, [26..27]=0

// workspace offsets (floats)
#define WS_WCAT   0        // [25][4624]
#define WS_BCAT   115600   // [4624]
#define WS_WCATT  120224   // [4611][28]   row d = [w[0..24], bias, 0, 0]
#define WS_M      249344   // [25][25]
#define WS_C      249984   // [25]
#define WS_BB     250016   // [1]
#define WS_PPAD   250048   // [8192][28]   [25] = -q/2
#define WS_Q      479424   // [8192]
#define WS_G2     487616   // [8192]
#define WS_RPAD   495808   // [8192][28]   [25] = -T/2
#define WS_WP2    725184   // [8192] min sq bits (prior->G)
#define WS_WW2    733376   // [8192] min sq bits (G->G, i!=j)
#define WS_ACC    741568   // recon accumulator
#define WS_H1T    741600   // [64][8192]
#define WS_H2T    1265888  // [64][8192]

__device__ inline float eluf(float x) { return x > 0.f ? x : expm1f(x); }

// dot of a wave-uniform 28-float row (25 weights + bias at [25]) with per-lane nx[25].
__device__ inline float sdot26(const float* __restrict__ WT, int rowidx, const float* nx) {
  const float* row = WT + (size_t)__builtin_amdgcn_readfirstlane(rowidx) * KE;
  float acc = row[25];
#pragma unroll
  for (int k = 0; k < 25; k++) acc = fmaf(row[k], nx[k], acc);
  return acc;
}

__global__ void k_init(float* ws) {
  int idx = blockIdx.x * 256 + threadIdx.x;
  unsigned int* u = (unsigned int*)ws;
  if (idx < BATCH)            u[WS_WP2 + idx] = 0x7F7FFFFFu;
  else if (idx < 2 * BATCH)   u[WS_WW2 + (idx - BATCH)] = 0x7F7FFFFFu;
  else if (idx == 2 * BATCH)  ws[WS_ACC] = 0.f;
}

__global__ void k_build(const float* __restrict__ w1W, const float* __restrict__ w1b,
                        const float* __restrict__ b1W, const float* __restrict__ b1b,
                        const float* __restrict__ w2W, const float* __restrict__ w2b,
                        const float* __restrict__ b2W, const float* __restrict__ b2b,
                        const float* __restrict__ w3W, const float* __restrict__ w3b,
                        const float* __restrict__ b3W, const float* __restrict__ b3b,
                        float* ws) {
  int idx = blockIdx.x * 256 + threadIdx.x;
  if (idx >= KN * D_G) return;
  int k = idx / D_G;
  int d = idx - k * D_G;
  float wv, bv;
  if (d < 192)       { int c = d;        wv = w1W[k*192  + c]; bv = w1b[c]; }
  else if (d < 256)  { int c = d - 192;  wv = b1W[k*64   + c]; bv = b1b[c]; }
  else if (d < 4352) { int c = d - 256;  wv = w2W[k*4096 + c]; bv = w2b[c]; }
  else if (d < 4416) { int c = d - 4352; wv = b2W[k*64   + c]; bv = b2b[c]; }
  else if (d < 4608) { int c = d - 4416; wv = w3W[k*192  + c]; bv = w3b[c]; }
  else               { int c = d - 4608; wv = b3W[k*3    + c]; bv = b3b[c]; }
  ws[WS_WCAT  + k * DGP + d] = wv;
  ws[WS_WCATT + d * KE  + k] = wv;
  if (k == 0) {
    ws[WS_BCAT + d] = bv;
    ws[WS_WCATT + d * KE + 25] = bv;
    ws[WS_WCATT + d * KE + 26] = 0.f;
    ws[WS_WCATT + d * KE + 27] = 0.f;
  }
}

// M = Wcat Wcat^T (25x25), c = Wcat bcat, bb = |bcat|^2
__global__ void k_M(float* ws) {
  const float* Wc = ws + WS_WCAT;
  const float* bc = ws + WS_BCAT;
  __shared__ float sred[256];
  int a = blockIdx.x, t = threadIdx.x;
  if (a < 25) {
    float acc[26];
#pragma unroll
    for (int v = 0; v < 26; v++) acc[v] = 0.f;
    for (int d = t; d < D_G; d += 256) {
      float va = Wc[a * DGP + d];
#pragma unroll
      for (int b = 0; b < 25; b++) acc[b] += va * Wc[b * DGP + d];
      acc[25] += va * bc[d];
    }
    for (int v = 0; v < 26; v++) {
      sred[t] = acc[v]; __syncthreads();
      for (int off = 128; off > 0; off >>= 1) { if (t < off) sred[t] += sred[t + off]; __syncthreads(); }
      if (t == 0) { if (v < 25) ws[WS_M + a * 25 + v] = sred[0]; else ws[WS_C + a] = sred[0]; }
      __syncthreads();
    }
  } else {
    float acc = 0.f;
    for (int d = t; d < D_G; d += 256) { float b = bc[d]; acc += b * b; }
    sred[t] = acc; __syncthreads();
    for (int off = 128; off > 0; off >>= 1) { if (t < off) sred[t] += sred[t + off]; __syncthreads(); }
    if (t == 0) ws[WS_BB] = sred[0];
  }
}

// PPAD rows, q, g2
__global__ void k_persample(const float* __restrict__ n, float* ws) {
  int j = blockIdx.x * 256 + threadIdx.x;
  if (j >= BATCH) return;
  const float* M  = ws + WS_M;
  const float* cv = ws + WS_C;
  float nr[25];
#pragma unroll
  for (int k = 0; k < 25; k++) nr[k] = n[j * 25 + k];
  float q = 0.f;
  for (int k2 = 0; k2 < 25; k2++) {
    float p = 0.f;
#pragma unroll
    for (int k1 = 0; k1 < 25; k1++) p += nr[k1] * M[k1 * 25 + k2];
    ws[WS_PPAD + j * KE + k2] = p;
    q += p * nr[k2];
  }
  float nc = 0.f;
#pragma unroll
  for (int k = 0; k < 25; k++) nc += nr[k] * cv[k];
  ws[WS_PPAD + j * KE + 25] = -0.5f * q;
  ws[WS_PPAD + j * KE + 26] = 0.f;
  ws[WS_PPAD + j * KE + 27] = 0.f;
  ws[WS_Q  + j] = q;
  ws[WS_G2 + j] = q + 2.f * nc + ws[WS_BB];
}

// RPAD rows: r_i = prior_i @ Wcat^T, [25] = -0.5*(|p_i|^2 - 2 p_i.bcat)
// 4 rows per wave, float4 d-tiling; Wc float4 loads amortized over 4 rows.
__global__ __launch_bounds__(256) void k_prior(const float* __restrict__ prior, float* ws) {
  const float* Wc = ws + WS_WCAT;
  const float* bc = ws + WS_BCAT;
  int wvid = blockIdx.x * 4 + (threadIdx.x >> 6);
  int l = threadIdx.x & 63;
  int i0 = wvid * 4;
  const float* pr0 = prior + (size_t)i0 * D_G;
  float racc[4][25];
  float sacc[4], p2acc[4];
#pragma unroll
  for (int r = 0; r < 4; r++) {
    sacc[r] = 0.f; p2acc[r] = 0.f;
#pragma unroll
    for (int k = 0; k < 25; k++) racc[r][k] = 0.f;
  }
  for (int it = 0; it < 18; ++it) {
    int d = it * 256 + 4 * l;
    float pv[4][4];
#pragma unroll
    for (int r = 0; r < 4; r++)
#pragma unroll
      for (int q = 0; q < 4; q++)
        pv[r][q] = pr0[(size_t)r * D_G + d + q];
    float4 bl = *(const float4*)(bc + d);
#pragma unroll
    for (int r = 0; r < 4; r++) {
      p2acc[r] += pv[r][0]*pv[r][0] + pv[r][1]*pv[r][1] + pv[r][2]*pv[r][2] + pv[r][3]*pv[r][3];
      sacc[r]  += pv[r][0]*bl.x + pv[r][1]*bl.y + pv[r][2]*bl.z + pv[r][3]*bl.w;
    }
#pragma unroll
    for (int k = 0; k < 25; k++) {
      float4 w = *(const float4*)(Wc + (size_t)k * DGP + d);
#pragma unroll
      for (int r = 0; r < 4; r++)
        racc[r][k] += pv[r][0]*w.x + pv[r][1]*w.y + pv[r][2]*w.z + pv[r][3]*w.w;
    }
  }
  if (l < 3) {             // d = 4608..4610 tail
    int d = 4608 + l;
#pragma unroll
    for (int r = 0; r < 4; r++) {
      float pvt = pr0[(size_t)r * D_G + d];
      p2acc[r] += pvt * pvt;
      sacc[r]  += pvt * bc[d];
#pragma unroll
      for (int k = 0; k < 25; k++) racc[r][k] += pvt * Wc[(size_t)k * DGP + d];
    }
  }
#pragma unroll
  for (int r = 0; r < 4; r++) {
#pragma unroll
    for (int k = 0; k < 25; k++) {
      float v = racc[r][k];
#pragma unroll
      for (int off = 32; off > 0; off >>= 1) v += __shfl_down(v, off, 64);
      if (l == 0) ws[WS_RPAD + (size_t)(i0 + r) * KE + k] = v;
    }
    float s = sacc[r], p2 = p2acc[r];
#pragma unroll
    for (int off = 32; off > 0; off >>= 1) { s += __shfl_down(s, off, 64); p2 += __shfl_down(p2, off, 64); }
    if (l == 0) {
      ws[WS_RPAD + (size_t)(i0 + r) * KE + 25] = -0.5f * (p2 - 2.f * s);
      ws[WS_RPAD + (size_t)(i0 + r) * KE + 26] = 0.f;
      ws[WS_RPAD + (size_t)(i0 + r) * KE + 27] = 0.f;
    }
  }
}

// min over i of (alpha_i + beta_j - 2 A_i.n_j), clamped >= 0.
// SGPR row stream feeds 2 j-columns per thread (2 independent FMA chains).
template <int SKIP>
__global__ __launch_bounds__(256) void k_pair(const float* __restrict__ APAD,
                                              const float* __restrict__ Bn,
                                              const float* __restrict__ beta,
                                              unsigned int* __restrict__ outm) {
  int t = threadIdx.x;
  int j0 = blockIdx.x * 512 + t;
  int j1 = j0 + 256;
  float nx0[25], nx1[25];
#pragma unroll
  for (int k = 0; k < 25; k++) { nx0[k] = Bn[j0 * 25 + k]; nx1[k] = Bn[j1 * 25 + k]; }
  float bj0 = beta[j0], bj1 = beta[j1];
  float mn0 = 3.402823466e38f, mn1 = 3.402823466e38f;
  int i0 = blockIdx.y * 128;
#pragma unroll 2
  for (int it = 0; it < 128; ++it) {
    int i = i0 + it;                               // wave-uniform
    const float* row = APAD + (size_t)__builtin_amdgcn_readfirstlane(i) * KE;
    float a0 = row[25], a1 = row[25];
#pragma unroll
    for (int k = 0; k < 25; k++) { a0 = fmaf(row[k], nx0[k], a0); a1 = fmaf(row[k], nx1[k], a1); }
    float sq0 = fmaxf(fmaf(-2.f, a0, bj0), 0.f);
    float sq1 = fmaxf(fmaf(-2.f, a1, bj1), 0.f);
    bool sk0 = SKIP && (i == j0);
    bool sk1 = SKIP && (i == j1);
    mn0 = sk0 ? mn0 : fminf(mn0, sq0);
    mn1 = sk1 ? mn1 : fminf(mn1, sq1);
  }
  atomicMin(&outm[j0], __float_as_uint(mn0));
  atomicMin(&outm[j1], __float_as_uint(mn1));
}

// decode phase 1: h1 = elu(W1 z + B1)
__global__ __launch_bounds__(64) void kd1(const float* __restrict__ n, const float* __restrict__ z,
                                          const float* __restrict__ ws_wt, float* __restrict__ h1t) {
  int s = blockIdx.x * 64 + threadIdx.x;
  int rb = blockIdx.y * 16;
  float nx[25];
#pragma unroll
  for (int k = 0; k < 25; k++) nx[k] = n[s * 25 + k];
  float zr[3];
#pragma unroll
  for (int d = 0; d < 3; d++) zr[d] = z[s * 3 + d];
  for (int r = 0; r < 16; r++) {
    int rr = rb + r;
    float acc = sdot26(ws_wt, 192 + rr, nx);                      // B1
#pragma unroll
    for (int d = 0; d < 3; d++)
      acc = fmaf(sdot26(ws_wt, rr * 3 + d, nx), zr[d], acc);      // W1
    h1t[rr * BATCH + s] = eluf(acc);
  }
}

// decode phase 2: h2 = elu(W2 h1 + B2)
__global__ __launch_bounds__(64) void kd2(const float* __restrict__ n,
                                          const float* __restrict__ ws_wt,
                                          const float* __restrict__ h1t, float* __restrict__ h2t) {
  int s = blockIdx.x * 64 + threadIdx.x;
  int rb = blockIdx.y * 4;
  float nx[25];
#pragma unroll
  for (int k = 0; k < 25; k++) nx[k] = n[s * 25 + k];
  float acc[4];
#pragma unroll
  for (int r = 0; r < 4; r++) acc[r] = sdot26(ws_wt, 4352 + rb + r, nx);   // B2
  for (int c = 0; c < 64; c++) {
    float h1c = h1t[c * BATCH + s];
#pragma unroll
    for (int r = 0; r < 4; r++) {
      float w = sdot26(ws_wt, 256 + (rb + r) * 64 + c, nx);                // W2
      acc[r] = fmaf(w, h1c, acc[r]);
    }
  }
#pragma unroll
  for (int r = 0; r < 4; r++) h2t[(rb + r) * BATCH + s] = eluf(acc[r]);
}

// decode phase 3: z_hat = W3 h2 + B3, recon partial
__global__ __launch_bounds__(64) void kd3(const float* __restrict__ n,
                                          const float* __restrict__ znext,
                                          const float* __restrict__ ws_wt,
                                          const float* __restrict__ h2t,
                                          float* __restrict__ out, float* __restrict__ accum) {
  int s = blockIdx.x * 64 + threadIdx.x;
  int r = blockIdx.y;
  float nx[25];
#pragma unroll
  for (int k = 0; k < 25; k++) nx[k] = n[s * 25 + k];
  float acc = sdot26(ws_wt, 4608 + r, nx);                                 // B3
  for (int c = 0; c < 64; c++)
    acc = fmaf(sdot26(ws_wt, 4416 + r * 64 + c, nx), h2t[c * BATCH + s], acc); // W3
  out[2 + s * 3 + r] = acc;
  float dz = acc - znext[s * 3 + r];
  float v = dz * dz;
#pragma unroll
  for (int off = 32; off > 0; off >>= 1) v += __shfl_down(v, off, 64);
  if (threadIdx.x == 0) atomicAdd(accum, v);
}

__global__ void k_finish(float* ws, float* __restrict__ out) {
  __shared__ float sred[256];
  int t = threadIdx.x;
  float part = 0.f;
  for (int j = t; j < BATCH; j += 256) {
    float wp2 = ws[WS_WP2 + j];
    float ww2 = ws[WS_WW2 + j];
    float wp = sqrtf(wp2 + 1e-8f);
    float ww = sqrtf(ww2 + 1e-8f);
    part += logf(wp / (ww + 1e-8f) + 1e-8f);
  }
  sred[t] = part; __syncthreads();
  for (int off = 128; off > 0; off >>= 1) { if (t < off) sred[t] += sred[t + off]; __syncthreads(); }
  if (t == 0) {
    float kl = sred[0] / (float)BATCH * (float)D_G + logf((float)BATCH / (float)(BATCH - 1));
    out[0] = ws[WS_ACC] / (float)BATCH;
    out[1] = kl;
  }
}

extern "C" void kernel_launch(void* const* d_in, const int* in_sizes, int n_in,
                              void* d_out, int out_size, void* d_ws, size_t ws_size,
                              hipStream_t stream) {
  (void)in_sizes; (void)n_in; (void)out_size; (void)ws_size;
  const float* z     = (const float*)d_in[0];
  const float* znext = (const float*)d_in[1];
  const float* n     = (const float*)d_in[2];
  const float* prior = (const float*)d_in[3];
  const float* w1W = (const float*)d_in[4];  const float* w1b = (const float*)d_in[5];
  const float* b1W = (const float*)d_in[6];  const float* b1b = (const float*)d_in[7];
  const float* w2W = (const float*)d_in[8];  const float* w2b = (const float*)d_in[9];
  const float* b2W = (const float*)d_in[10]; const float* b2b = (const float*)d_in[11];
  const float* w3W = (const float*)d_in[12]; const float* w3b = (const float*)d_in[13];
  const float* b3W = (const float*)d_in[14]; const float* b3b = (const float*)d_in[15];
  float* out = (float*)d_out;
  float* ws  = (float*)d_ws;

  k_init<<<dim3(65), dim3(256), 0, stream>>>(ws);
  k_build<<<dim3((KN * D_G + 255) / 256), dim3(256), 0, stream>>>(
      w1W, w1b, b1W, b1b, w2W, w2b, b2W, b2b, w3W, w3b, b3W, b3b, ws);
  k_M<<<dim3(26), dim3(256), 0, stream>>>(ws);
  k_persample<<<dim3(32), dim3(256), 0, stream>>>(n, ws);
  k_prior<<<dim3(512), dim3(256), 0, stream>>>(prior, ws);
  k_pair<1><<<dim3(16, 64), dim3(256), 0, stream>>>(ws + WS_PPAD, n, ws + WS_Q,
                                                    (unsigned int*)(ws + WS_WW2));
  k_pair<0><<<dim3(16, 64), dim3(256), 0, stream>>>(ws + WS_RPAD, n, ws + WS_G2,
                                                    (unsigned int*)(ws + WS_WP2));
  kd1<<<dim3(128, 4), dim3(64), 0, stream>>>(n, z, ws + WS_WCATT, ws + WS_H1T);
  kd2<<<dim3(128, 16), dim3(64), 0, stream>>>(n, ws + WS_WCATT, ws + WS_H1T, ws + WS_H2T);
  kd3<<<dim3(128, 3), dim3(64), 0, stream>>>(n, znext, ws + WS_WCATT, ws + WS_H2T, out, ws + WS_ACC);
  k_finish<<<dim3(1), dim3(256), 0, stream>>>(ws, out);
}

// Round 4
// 664.450 us; speedup vs baseline: 1.5101x; 1.0708x over previous
//
#include <hip/hip_runtime.h>
#include <math.h>

#define BATCH 8192
#define D_G   4611
#define DGP   4624   // padded Wcat row stride (multiple of 16 floats for aligned float4)
#define KN    25
#define KE    28     // padded row: 25 weights, [25]=bias/alpha slot, [26..27]=0

// workspace offsets (floats)
#define WS_WCAT   0        // [25][4624]
#define WS_BCAT   115600   // [4624]
#define WS_WCATT  120224   // [4611][28]   row d = [w[0..24], bias, 0, 0]
#define WS_M      249344   // [25][25]
#define WS_C      249984   // [25]
#define WS_BB     250016   // [1]
#define WS_PPAD   250048   // [8192][28]   [25] = -q/2
#define WS_Q      479424   // [8192]
#define WS_G2     487616   // [8192]
#define WS_RPAD   495808   // [8192][28]   [25] = -T/2
#define WS_WP2    725184   // [8192] min sq bits (prior->G)
#define WS_WW2    733376   // [8192] min sq bits (G->G, i!=j)
#define WS_ACC    741568   // recon accumulator
#define WS_H1T    741600   // [64][8192]
#define WS_H2T    1265888  // [64][8192]

__device__ inline float eluf(float x) { return x > 0.f ? x : expm1f(x); }

// dot of a wave-uniform 28-float row (25 weights + bias at [25]) with per-lane nx[25].
__device__ inline float sdot26(const float* __restrict__ WT, int rowidx, const float* nx) {
  const float* row = WT + (size_t)__builtin_amdgcn_readfirstlane(rowidx) * KE;
  float acc = row[25];
#pragma unroll
  for (int k = 0; k < 25; k++) acc = fmaf(row[k], nx[k], acc);
  return acc;
}

__global__ void k_init(float* ws) {
  int idx = blockIdx.x * 256 + threadIdx.x;
  unsigned int* u = (unsigned int*)ws;
  if (idx < BATCH)            u[WS_WP2 + idx] = 0x7F7FFFFFu;
  else if (idx < 2 * BATCH)   u[WS_WW2 + (idx - BATCH)] = 0x7F7FFFFFu;
  else if (idx == 2 * BATCH)  ws[WS_ACC] = 0.f;
}

__global__ void k_build(const float* __restrict__ w1W, const float* __restrict__ w1b,
                        const float* __restrict__ b1W, const float* __restrict__ b1b,
                        const float* __restrict__ w2W, const float* __restrict__ w2b,
                        const float* __restrict__ b2W, const float* __restrict__ b2b,
                        const float* __restrict__ w3W, const float* __restrict__ w3b,
                        const float* __restrict__ b3W, const float* __restrict__ b3b,
                        float* ws) {
  int idx = blockIdx.x * 256 + threadIdx.x;
  if (idx >= KN * D_G) return;
  int k = idx / D_G;
  int d = idx - k * D_G;
  float wv, bv;
  if (d < 192)       { int c = d;        wv = w1W[k*192  + c]; bv = w1b[c]; }
  else if (d < 256)  { int c = d - 192;  wv = b1W[k*64   + c]; bv = b1b[c]; }
  else if (d < 4352) { int c = d - 256;  wv = w2W[k*4096 + c]; bv = w2b[c]; }
  else if (d < 4416) { int c = d - 4352; wv = b2W[k*64   + c]; bv = b2b[c]; }
  else if (d < 4608) { int c = d - 4416; wv = w3W[k*192  + c]; bv = w3b[c]; }
  else               { int c = d - 4608; wv = b3W[k*3    + c]; bv = b3b[c]; }
  ws[WS_WCAT  + k * DGP + d] = wv;
  ws[WS_WCATT + d * KE  + k] = wv;
  if (k == 0) {
    ws[WS_BCAT + d] = bv;
    ws[WS_WCATT + d * KE + 25] = bv;
    ws[WS_WCATT + d * KE + 26] = 0.f;
    ws[WS_WCATT + d * KE + 27] = 0.f;
  }
}

// M = Wcat Wcat^T (25x25), c = Wcat bcat, bb = |bcat|^2 — shfl-based reduction
__global__ __launch_bounds__(256) void k_M(float* ws) {
  const float* Wc = ws + WS_WCAT;
  const float* bc = ws + WS_BCAT;
  __shared__ float part[4][26];
  int a = blockIdx.x, t = threadIdx.x;
  int wv = t >> 6, l = t & 63;
  if (a < 25) {
    float acc[26];
#pragma unroll
    for (int v = 0; v < 26; v++) acc[v] = 0.f;
    for (int d = t; d < D_G; d += 256) {
      float va = Wc[a * DGP + d];
#pragma unroll
      for (int b = 0; b < 25; b++) acc[b] += va * Wc[b * DGP + d];
      acc[25] += va * bc[d];
    }
#pragma unroll
    for (int v = 0; v < 26; v++) {
      float x = acc[v];
#pragma unroll
      for (int off = 32; off > 0; off >>= 1) x += __shfl_down(x, off, 64);
      if (l == 0) part[wv][v] = x;
    }
    __syncthreads();
    if (t < 26) {
      float s = part[0][t] + part[1][t] + part[2][t] + part[3][t];
      if (t < 25) ws[WS_M + a * 25 + t] = s; else ws[WS_C + a] = s;
    }
  } else {
    float acc = 0.f;
    for (int d = t; d < D_G; d += 256) { float b = bc[d]; acc += b * b; }
#pragma unroll
    for (int off = 32; off > 0; off >>= 1) acc += __shfl_down(acc, off, 64);
    if (l == 0) part[wv][0] = acc;
    __syncthreads();
    if (t == 0) ws[WS_BB] = part[0][0] + part[1][0] + part[2][0] + part[3][0];
  }
}

// PPAD rows, q, g2
__global__ void k_persample(const float* __restrict__ n, float* ws) {
  int j = blockIdx.x * 256 + threadIdx.x;
  if (j >= BATCH) return;
  const float* M  = ws + WS_M;
  const float* cv = ws + WS_C;
  float nr[25];
#pragma unroll
  for (int k = 0; k < 25; k++) nr[k] = n[j * 25 + k];
  float q = 0.f;
  for (int k2 = 0; k2 < 25; k2++) {
    float p = 0.f;
#pragma unroll
    for (int k1 = 0; k1 < 25; k1++) p += nr[k1] * M[k1 * 25 + k2];
    ws[WS_PPAD + j * KE + k2] = p;
    q += p * nr[k2];
  }
  float nc = 0.f;
#pragma unroll
  for (int k = 0; k < 25; k++) nc += nr[k] * cv[k];
  ws[WS_PPAD + j * KE + 25] = -0.5f * q;
  ws[WS_PPAD + j * KE + 26] = 0.f;
  ws[WS_PPAD + j * KE + 27] = 0.f;
  ws[WS_Q  + j] = q;
  ws[WS_G2 + j] = q + 2.f * nc + ws[WS_BB];
}

// RPAD rows: r_i = prior_i @ Wcat^T, [25] = -0.5*(|p_i|^2 - 2 p_i.bcat)
// Block = 16 rows (4/wave). Wc+bc d-chunk (256 wide) staged in LDS, shared by 4 waves.
__global__ __launch_bounds__(256) void k_prior(const float* __restrict__ prior, float* ws) {
  __shared__ float wlds[26 * 256];     // rows 0..24 = Wc chunk, row 25 = bc chunk
  const float* Wc = ws + WS_WCAT;
  const float* bc = ws + WS_BCAT;
  int t = threadIdx.x;
  int wv = t >> 6, l = t & 63;
  int i0 = (blockIdx.x * 4 + wv) * 4;  // 4 rows per wave
  const float* pr0 = prior + (size_t)i0 * D_G;
  float racc[4][25];
  float sacc[4], p2acc[4];
#pragma unroll
  for (int r = 0; r < 4; r++) {
    sacc[r] = 0.f; p2acc[r] = 0.f;
#pragma unroll
    for (int k = 0; k < 25; k++) racc[r][k] = 0.f;
  }
  for (int ch = 0; ch < 18; ++ch) {
    int dbase = ch * 256;
    __syncthreads();                   // prev-chunk reads done
    for (int idx = t; idx < 26 * 64; idx += 256) {
      int k = idx >> 6, c4 = (idx & 63) * 4;
      const float* src = (k < 25 ? Wc + (size_t)k * DGP : bc) + dbase + c4;
      *(float4*)&wlds[k * 256 + c4] = *(const float4*)src;
    }
    __syncthreads();
    int d = dbase + 4 * l;
    float pv[4][4];
#pragma unroll
    for (int r = 0; r < 4; r++)
#pragma unroll
      for (int q = 0; q < 4; q++)
        pv[r][q] = pr0[(size_t)r * D_G + d + q];
    float4 bl = *(const float4*)&wlds[25 * 256 + 4 * l];
#pragma unroll
    for (int r = 0; r < 4; r++) {
      p2acc[r] += pv[r][0]*pv[r][0] + pv[r][1]*pv[r][1] + pv[r][2]*pv[r][2] + pv[r][3]*pv[r][3];
      sacc[r]  += pv[r][0]*bl.x + pv[r][1]*bl.y + pv[r][2]*bl.z + pv[r][3]*bl.w;
    }
#pragma unroll
    for (int k = 0; k < 25; k++) {
      float4 w = *(const float4*)&wlds[k * 256 + 4 * l];
#pragma unroll
      for (int r = 0; r < 4; r++)
        racc[r][k] += pv[r][0]*w.x + pv[r][1]*w.y + pv[r][2]*w.z + pv[r][3]*w.w;
    }
  }
  if (l < 3) {             // d = 4608..4610 tail
    int d = 4608 + l;
#pragma unroll
    for (int r = 0; r < 4; r++) {
      float pvt = pr0[(size_t)r * D_G + d];
      p2acc[r] += pvt * pvt;
      sacc[r]  += pvt * bc[d];
#pragma unroll
      for (int k = 0; k < 25; k++) racc[r][k] += pvt * Wc[(size_t)k * DGP + d];
    }
  }
#pragma unroll
  for (int r = 0; r < 4; r++) {
#pragma unroll
    for (int k = 0; k < 25; k++) {
      float v = racc[r][k];
#pragma unroll
      for (int off = 32; off > 0; off >>= 1) v += __shfl_down(v, off, 64);
      if (l == 0) ws[WS_RPAD + (size_t)(i0 + r) * KE + k] = v;
    }
    float s = sacc[r], p2 = p2acc[r];
#pragma unroll
    for (int off = 32; off > 0; off >>= 1) { s += __shfl_down(s, off, 64); p2 += __shfl_down(p2, off, 64); }
    if (l == 0) {
      ws[WS_RPAD + (size_t)(i0 + r) * KE + 25] = -0.5f * (p2 - 2.f * s);
      ws[WS_RPAD + (size_t)(i0 + r) * KE + 26] = 0.f;
      ws[WS_RPAD + (size_t)(i0 + r) * KE + 27] = 0.f;
    }
  }
}

// min over i of (alpha_i + beta_j - 2 A_i.n_j), clamped >= 0.
// 256-row i-slice staged in LDS (coalesced); inner loop = wave-uniform LDS row
// feeding 2 independent 26-FMA chains per thread (JT=2).
template <int SKIP>
__global__ __launch_bounds__(256) void k_pair(const float* __restrict__ APAD,
                                              const float* __restrict__ Bn,
                                              const float* __restrict__ beta,
                                              unsigned int* __restrict__ outm) {
  __shared__ float rows[256 * KE];     // 28672 B
  int t = threadIdx.x;
  int jbase = blockIdx.y * 256;
  {
    const float4* src = (const float4*)(APAD + (size_t)jbase * KE);
    float4* dst = (float4*)rows;
#pragma unroll
    for (int u = 0; u < 7; u++) dst[t + 256 * u] = src[t + 256 * u];
  }
  int j0 = blockIdx.x * 512 + t;
  int j1 = j0 + 256;
  float nx0[25], nx1[25];
#pragma unroll
  for (int k = 0; k < 25; k++) { nx0[k] = Bn[j0 * 25 + k]; nx1[k] = Bn[j1 * 25 + k]; }
  float bj0 = beta[j0], bj1 = beta[j1];
  float mn0 = 3.402823466e38f, mn1 = 3.402823466e38f;
  __syncthreads();
#pragma unroll 2
  for (int it = 0; it < 256; ++it) {
    const float* row = rows + it * KE;             // wave-uniform LDS address
    float a0 = row[25], a1 = row[25];
#pragma unroll
    for (int k = 0; k < 25; k++) { a0 = fmaf(row[k], nx0[k], a0); a1 = fmaf(row[k], nx1[k], a1); }
    float sq0 = fmaxf(fmaf(-2.f, a0, bj0), 0.f);
    float sq1 = fmaxf(fmaf(-2.f, a1, bj1), 0.f);
    int i = jbase + it;
    bool sk0 = SKIP && (i == j0);
    bool sk1 = SKIP && (i == j1);
    mn0 = sk0 ? mn0 : fminf(mn0, sq0);
    mn1 = sk1 ? mn1 : fminf(mn1, sq1);
  }
  atomicMin(&outm[j0], __float_as_uint(mn0));
  atomicMin(&outm[j1], __float_as_uint(mn1));
}

// decode phase 1: h1 = elu(W1 z + B1)
__global__ __launch_bounds__(64) void kd1(const float* __restrict__ n, const float* __restrict__ z,
                                          const float* __restrict__ ws_wt, float* __restrict__ h1t) {
  int s = blockIdx.x * 64 + threadIdx.x;
  int rb = blockIdx.y * 16;
  float nx[25];
#pragma unroll
  for (int k = 0; k < 25; k++) nx[k] = n[s * 25 + k];
  float zr[3];
#pragma unroll
  for (int d = 0; d < 3; d++) zr[d] = z[s * 3 + d];
  for (int r = 0; r < 16; r++) {
    int rr = rb + r;
    float acc = sdot26(ws_wt, 192 + rr, nx);                      // B1
#pragma unroll
    for (int d = 0; d < 3; d++)
      acc = fmaf(sdot26(ws_wt, rr * 3 + d, nx), zr[d], acc);      // W1
    h1t[rr * BATCH + s] = eluf(acc);
  }
}

// decode phase 2: h2 = elu(W2 h1 + B2)
__global__ __launch_bounds__(64) void kd2(const float* __restrict__ n,
                                          const float* __restrict__ ws_wt,
                                          const float* __restrict__ h1t, float* __restrict__ h2t) {
  int s = blockIdx.x * 64 + threadIdx.x;
  int rb = blockIdx.y * 4;
  float nx[25];
#pragma unroll
  for (int k = 0; k < 25; k++) nx[k] = n[s * 25 + k];
  float acc[4];
#pragma unroll
  for (int r = 0; r < 4; r++) acc[r] = sdot26(ws_wt, 4352 + rb + r, nx);   // B2
  for (int c = 0; c < 64; c++) {
    float h1c = h1t[c * BATCH + s];
#pragma unroll
    for (int r = 0; r < 4; r++) {
      float w = sdot26(ws_wt, 256 + (rb + r) * 64 + c, nx);                // W2
      acc[r] = fmaf(w, h1c, acc[r]);
    }
  }
#pragma unroll
  for (int r = 0; r < 4; r++) h2t[(rb + r) * BATCH + s] = eluf(acc[r]);
}

// decode phase 3: z_hat = W3 h2 + B3, recon partial
__global__ __launch_bounds__(64) void kd3(const float* __restrict__ n,
                                          const float* __restrict__ znext,
                                          const float* __restrict__ ws_wt,
                                          const float* __restrict__ h2t,
                                          float* __restrict__ out, float* __restrict__ accum) {
  int s = blockIdx.x * 64 + threadIdx.x;
  int r = blockIdx.y;
  float nx[25];
#pragma unroll
  for (int k = 0; k < 25; k++) nx[k] = n[s * 25 + k];
  float acc = sdot26(ws_wt, 4608 + r, nx);                                 // B3
  for (int c = 0; c < 64; c++)
    acc = fmaf(sdot26(ws_wt, 4416 + r * 64 + c, nx), h2t[c * BATCH + s], acc); // W3
  out[2 + s * 3 + r] = acc;
  float dz = acc - znext[s * 3 + r];
  float v = dz * dz;
#pragma unroll
  for (int off = 32; off > 0; off >>= 1) v += __shfl_down(v, off, 64);
  if (threadIdx.x == 0) atomicAdd(accum, v);
}

__global__ void k_finish(float* ws, float* __restrict__ out) {
  __shared__ float sred[256];
  int t = threadIdx.x;
  float part = 0.f;
  for (int j = t; j < BATCH; j += 256) {
    float wp2 = ws[WS_WP2 + j];
    float ww2 = ws[WS_WW2 + j];
    float wp = sqrtf(wp2 + 1e-8f);
    float ww = sqrtf(ww2 + 1e-8f);
    part += logf(wp / (ww + 1e-8f) + 1e-8f);
  }
  sred[t] = part; __syncthreads();
  for (int off = 128; off > 0; off >>= 1) { if (t < off) sred[t] += sred[t + off]; __syncthreads(); }
  if (t == 0) {
    float kl = sred[0] / (float)BATCH * (float)D_G + logf((float)BATCH / (float)(BATCH - 1));
    out[0] = ws[WS_ACC] / (float)BATCH;
    out[1] = kl;
  }
}

extern "C" void kernel_launch(void* const* d_in, const int* in_sizes, int n_in,
                              void* d_out, int out_size, void* d_ws, size_t ws_size,
                              hipStream_t stream) {
  (void)in_sizes; (void)n_in; (void)out_size; (void)ws_size;
  const float* z     = (const float*)d_in[0];
  const float* znext = (const float*)d_in[1];
  const float* n     = (const float*)d_in[2];
  const float* prior = (const float*)d_in[3];
  const float* w1W = (const float*)d_in[4];  const float* w1b = (const float*)d_in[5];
  const float* b1W = (const float*)d_in[6];  const float* b1b = (const float*)d_in[7];
  const float* w2W = (const float*)d_in[8];  const float* w2b = (const float*)d_in[9];
  const float* b2W = (const float*)d_in[10]; const float* b2b = (const float*)d_in[11];
  const float* w3W = (const float*)d_in[12]; const float* w3b = (const float*)d_in[13];
  const float* b3W = (const float*)d_in[14]; const float* b3b = (const float*)d_in[15];
  float* out = (float*)d_out;
  float* ws  = (float*)d_ws;

  k_init<<<dim3(65), dim3(256), 0, stream>>>(ws);
  k_build<<<dim3((KN * D_G + 255) / 256), dim3(256), 0, stream>>>(
      w1W, w1b, b1W, b1b, w2W, w2b, b2W, b2b, w3W, w3b, b3W, b3b, ws);
  k_M<<<dim3(26), dim3(256), 0, stream>>>(ws);
  k_persample<<<dim3(32), dim3(256), 0, stream>>>(n, ws);
  k_prior<<<dim3(512), dim3(256), 0, stream>>>(prior, ws);
  k_pair<1><<<dim3(16, 32), dim3(256), 0, stream>>>(ws + WS_PPAD, n, ws + WS_Q,
                                                    (unsigned int*)(ws + WS_WW2));
  k_pair<0><<<dim3(16, 32), dim3(256), 0, stream>>>(ws + WS_RPAD, n, ws + WS_G2,
                                                    (unsigned int*)(ws + WS_WP2));
  kd1<<<dim3(128, 4), dim3(64), 0, stream>>>(n, z, ws + WS_WCATT, ws + WS_H1T);
  kd2<<<dim3(128, 16), dim3(64), 0, stream>>>(n, ws + WS_WCATT, ws + WS_H1T, ws + WS_H2T);
  kd3<<<dim3(128, 3), dim3(64), 0, stream>>>(n, znext, ws + WS_WCATT, ws + WS_H2T, out, ws + WS_ACC);
  k_finish<<<dim3(1), dim3(256), 0, stream>>>(ws, out);
}